// Round 6
// baseline (372.396 us; speedup 1.0000x reference)
//
#include <hip/hip_runtime.h>
#include <hip/hip_cooperative_groups.h>

namespace cg = cooperative_groups;

#define T_ 16
#define N_ 128
#define F_ 128

__device__ __forceinline__ float fast_tanh(float x) {
    // tanh(x) = 1 - 2/(exp(2x)+1); v_exp_f32 + native rcp-div. Handles +-inf correctly.
    float e = __expf(2.0f * x);
    return 1.0f - __fdividef(2.0f, e + 1.0f);
}

__device__ __forceinline__ float lrelu(float v) {
    return v >= 0.0f ? v : 0.01f * v;
}

// ---------------- dispatch 1: sim_cal(x0) + (role-split) W transpose + bn zero ----------------
// grid (16, 17) x 256. by<16: sim blocks (t=bx, ch=by). by==16: prep blocks.
__global__ __launch_bounds__(256) void sim0_prep_k(const float* __restrict__ x,
                                                   const float* __restrict__ W,
                                                   float* __restrict__ WT,
                                                   float* __restrict__ bn,
                                                   float* __restrict__ out) {
    __shared__ float Xs[128][132];
    __shared__ float nrm[128];
    int tid = threadIdx.x;

    if (blockIdx.y == 16) {
        int idx4 = blockIdx.x * 256 + tid;       // 0..4095
        #pragma unroll
        for (int k = 0; k < 8; ++k) {
            int lin = k * 4096 + idx4;           // 0..32767
            int l = lin >> 14, idx = lin & 16383;
            int g = idx >> 7, f = idx & 127;
            WT[l * 16384 + f * 128 + g] = W[lin];
        }
        if (blockIdx.x == 0) { bn[tid] = 0.0f; bn[256 + tid] = 0.0f; }
        return;
    }

    int t = blockIdx.x, ch = blockIdx.y;
    int m = tid & 127, rh = tid >> 7;
    const float* xt = x + (size_t)t * (N_ * F_);
    int fg = (tid & 31) * 4, ko = tid >> 5;

    for (int kb = 0; kb < 128; kb += 8) {
        int k = kb + ko;
        *(float4*)&Xs[k][fg] = *(const float4*)(xt + k * 128 + fg);
    }
    __syncthreads();

    if (tid < 128) {
        float s = 0.0f;
        #pragma unroll 8
        for (int f = 0; f < 128; f += 4) {
            float4 v = *(float4*)&Xs[m][f];
            s += v.x * v.x + v.y * v.y + v.z * v.z + v.w * v.w;
        }
        nrm[m] = sqrtf(s);
    }
    __syncthreads();

    float acc[4];
    #pragma unroll
    for (int r = 0; r < 4; ++r) acc[r] = 0.0f;

    for (int fc = 0; fc < 128; fc += 32) {
        float xm[32];
        #pragma unroll
        for (int f = 0; f < 32; f += 4) {
            float4 v = *(float4*)&Xs[m][fc + f];
            xm[f] = v.x; xm[f + 1] = v.y; xm[f + 2] = v.z; xm[f + 3] = v.w;
        }
        #pragma unroll
        for (int r = 0; r < 4; ++r) {
            int n = ch * 8 + rh * 4 + r;
            #pragma unroll
            for (int f = 0; f < 32; f += 4) {
                float4 v = *(float4*)&Xs[n][fc + f];
                acc[r] = fmaf(xm[f], v.x,
                         fmaf(xm[f + 1], v.y,
                         fmaf(xm[f + 2], v.z,
                         fmaf(xm[f + 3], v.w, acc[r]))));
            }
        }
    }

    float nm = nrm[m];
    size_t ob = (size_t)t * 2 * 16384;
    #pragma unroll
    for (int r = 0; r < 4; ++r) {
        int n = ch * 8 + rh * 4 + r;
        float denom = nrm[n] * nm + 1e-6f;
        float sim = __fdividef(acc[r], denom);
        out[ob + (size_t)n * 128 + m] = fminf(fmaxf(sim, 0.0f), 1.0f);
        out[ob + 16384 + (size_t)n * 128 + m] = fminf(fmaxf(1.0f - sim, 0.0f), 1.0f);
    }
}

// ---------------- edge update + partial aggregate (unchanged from round 5) ----------------
// grid 8192 (= (t*128+i)*4 + quarter), block 256 (jl 0..7, fg 0..31).
template<int LAYER>
__global__ __launch_bounds__(256) void edge_k(const float* __restrict__ x0,
                                              const float* __restrict__ x1,
                                              const float* __restrict__ E,
                                              const float* __restrict__ ew,
                                              const float* __restrict__ eb,
                                              float* __restrict__ aggrP) {
    __shared__ float4 red[256];
    int b = blockIdx.x;
    int ti = b >> 2, q = b & 3;          // ti = t*128+i, q = j-quarter
    int t = ti >> 7, i = ti & 127;
    int tid = threadIdx.x, jl = tid >> 5, fg = tid & 31;

    const float4* xt0 = (const float4*)(x0 + (size_t)t * 16384);
    const float4* xt1 = (const float4*)(x1 + (size_t)t * 16384);
    const float4* Ei  = (const float4*)(E + (size_t)ti * 16384);

    float w02 = ew[2], b0 = eb[0];
    float c0 = ew[0] + ew[1], nw01 = -ew[1];
    float c1 = 0.f, nw11 = 0.f, w12 = 0.f, b1 = 0.f;
    if constexpr (LAYER == 1) { c1 = ew[3] + ew[4]; nw11 = -ew[4]; w12 = ew[5]; b1 = eb[1]; }

    float4 xi0 = xt0[i * 32 + fg];
    float4 xi1 = xi0;
    if constexpr (LAYER == 1) xi1 = xt1[i * 32 + fg];

    float4 a = make_float4(0.f, 0.f, 0.f, 0.f);
    int jbase = q * 32;

    float4 xj0[4], ev[4], xj1[4];
    #pragma unroll
    for (int k = 0; k < 4; ++k) {
        int j = jbase + k * 8 + jl;
        ev[k]  = Ei[j * 32 + fg];
        xj0[k] = xt0[j * 32 + fg];
        if constexpr (LAYER == 1) xj1[k] = xt1[j * 32 + fg];
    }

    #pragma unroll
    for (int k = 0; k < 4; ++k) {
        int j = jbase + k * 8 + jl;
        float msk = (j != i) ? 1.0f : 0.0f;
        if constexpr (LAYER == 0) {
            a.x += msk * fast_tanh(fmaf(c0, xi0.x, fmaf(w02, ev[k].x, fmaf(nw01, xj0[k].x, b0))));
            a.y += msk * fast_tanh(fmaf(c0, xi0.y, fmaf(w02, ev[k].y, fmaf(nw01, xj0[k].y, b0))));
            a.z += msk * fast_tanh(fmaf(c0, xi0.z, fmaf(w02, ev[k].z, fmaf(nw01, xj0[k].z, b0))));
            a.w += msk * fast_tanh(fmaf(c0, xi0.w, fmaf(w02, ev[k].w, fmaf(nw01, xj0[k].w, b0))));
        } else {
            float e0x = fast_tanh(fmaf(c0, xi0.x, fmaf(w02, ev[k].x, fmaf(nw01, xj0[k].x, b0))));
            float e0y = fast_tanh(fmaf(c0, xi0.y, fmaf(w02, ev[k].y, fmaf(nw01, xj0[k].y, b0))));
            float e0z = fast_tanh(fmaf(c0, xi0.z, fmaf(w02, ev[k].z, fmaf(nw01, xj0[k].z, b0))));
            float e0w = fast_tanh(fmaf(c0, xi0.w, fmaf(w02, ev[k].w, fmaf(nw01, xj0[k].w, b0))));
            a.x += msk * fast_tanh(fmaf(c1, xi1.x, fmaf(w12, e0x, fmaf(nw11, xj1[k].x, b1))));
            a.y += msk * fast_tanh(fmaf(c1, xi1.y, fmaf(w12, e0y, fmaf(nw11, xj1[k].y, b1))));
            a.z += msk * fast_tanh(fmaf(c1, xi1.z, fmaf(w12, e0z, fmaf(nw11, xj1[k].z, b1))));
            a.w += msk * fast_tanh(fmaf(c1, xi1.w, fmaf(w12, e0w, fmaf(nw11, xj1[k].w, b1))));
        }
    }

    red[tid] = a;
    __syncthreads();
    if (tid < 32) {
        float4 r = red[tid];
        #pragma unroll
        for (int k = 1; k < 8; ++k) {
            float4 o = red[tid + 32 * k];
            r.x += o.x; r.y += o.y; r.z += o.z; r.w += o.w;
        }
        ((float4*)(aggrP + (size_t)q * 262144))[ti * 32 + tid] = r;
    }
}

// ---------------- cooperative: node update + BN stats -> grid sync -> BN apply + sim ----------------
// grid (16,16) x 256. Phase 1 = node_k (8 rows/block, f-split halves, y->yb, BN atomics).
// grid.sync(). Phase 2 = sim_k<BN> on yb (ch==0 writes x_next if WRITE_X).
union NodeSimShared {
    struct { float hs[8][128]; float ya[8][128]; } n;
    struct { float Xs[128][132]; float nrm[128]; } s;
};

template<bool WRITE_X>
__global__ __launch_bounds__(256) void node_sim_k(const float* __restrict__ x,
                                                  const float* __restrict__ aggrP,
                                                  const float* __restrict__ cw,
                                                  const float* __restrict__ WT,
                                                  float* __restrict__ yb,
                                                  float* __restrict__ bnL,
                                                  const float* __restrict__ gamma,
                                                  const float* __restrict__ beta,
                                                  float* __restrict__ out,
                                                  float* __restrict__ xout) {
    __shared__ NodeSimShared sm;
    int t = blockIdx.x, ch = blockIdx.y;
    int tid = threadIdx.x;
    int g = tid & 127, half = tid >> 7;
    size_t base = ((size_t)t * 128 + ch * 8) * 128;

    // ---- phase 1: node update ----
    {
        float c0 = cw[0], c1 = cw[1];
        #pragma unroll
        for (int rr = 0; rr < 4; ++rr) {
            int r = half * 4 + rr;
            size_t o = base + (size_t)r * 128 + g;
            float xv = x[o];
            float av = aggrP[o] + aggrP[262144 + o] + aggrP[524288 + o] + aggrP[786432 + o];
            sm.n.hs[r][g] = lrelu(fmaf(c0, xv, c1 * av));
        }
        __syncthreads();
        float acc[8];
        #pragma unroll
        for (int r = 0; r < 8; ++r) acc[r] = 0.0f;
        const float* wp = WT + (size_t)(half * 64) * 128 + g;
        #pragma unroll 4
        for (int f = 0; f < 64; ++f) {
            float wv = wp[(size_t)f * 128];
            #pragma unroll
            for (int r = 0; r < 8; ++r) acc[r] = fmaf(sm.n.hs[r][half * 64 + f], wv, acc[r]);
        }
        if (half) {
            #pragma unroll
            for (int r = 0; r < 8; ++r) sm.n.ya[r][g] = acc[r];
        }
        __syncthreads();
        if (!half) {
            float s = 0.0f, ss = 0.0f;
            #pragma unroll
            for (int r = 0; r < 8; ++r) {
                float y = acc[r] + sm.n.ya[r][g];
                yb[base + (size_t)r * 128 + g] = y;
                s += y;
                ss += y * y;
            }
            atomicAdd(&bnL[g], s);
            atomicAdd(&bnL[128 + g], ss);
        }
    }

    cg::this_grid().sync();

    // ---- phase 2: BN apply + lrelu + sim (+ x_next writeback from ch==0) ----
    int m = g, rh = half;
    const float* xt = yb + (size_t)t * (N_ * F_);
    int fg = (tid & 31) * 4, ko = tid >> 5;

    float4 sc, sh;   // y*sc + sh == (y-mu)*inv*gamma + beta
    {
        float4 s1 = *(const float4*)(bnL + fg);
        float4 s2 = *(const float4*)(bnL + 128 + fg);
        float4 ga = *(const float4*)(gamma + fg);
        float4 be = *(const float4*)(beta + fg);
        const float inv_n = 1.0f / 2048.0f;
        float mx = s1.x * inv_n, my = s1.y * inv_n, mz = s1.z * inv_n, mw = s1.w * inv_n;
        sc.x = rsqrtf(s2.x * inv_n - mx * mx + 1e-5f) * ga.x;
        sc.y = rsqrtf(s2.y * inv_n - my * my + 1e-5f) * ga.y;
        sc.z = rsqrtf(s2.z * inv_n - mz * mz + 1e-5f) * ga.z;
        sc.w = rsqrtf(s2.w * inv_n - mw * mw + 1e-5f) * ga.w;
        sh.x = be.x - mx * sc.x;
        sh.y = be.y - my * sc.y;
        sh.z = be.z - mz * sc.z;
        sh.w = be.w - mw * sc.w;
    }

    bool wout = WRITE_X && (ch == 0);
    for (int kb = 0; kb < 128; kb += 8) {
        int k = kb + ko;
        float4 v = *(const float4*)(xt + k * 128 + fg);
        v.x = lrelu(fmaf(v.x, sc.x, sh.x));
        v.y = lrelu(fmaf(v.y, sc.y, sh.y));
        v.z = lrelu(fmaf(v.z, sc.z, sh.z));
        v.w = lrelu(fmaf(v.w, sc.w, sh.w));
        if (wout) *(float4*)(xout + (size_t)t * 16384 + k * 128 + fg) = v;
        *(float4*)&sm.s.Xs[k][fg] = v;
    }
    __syncthreads();

    if (tid < 128) {
        float s = 0.0f;
        #pragma unroll 8
        for (int f = 0; f < 128; f += 4) {
            float4 v = *(float4*)&sm.s.Xs[m][f];
            s += v.x * v.x + v.y * v.y + v.z * v.z + v.w * v.w;
        }
        sm.s.nrm[m] = sqrtf(s);
    }
    __syncthreads();

    float acc[4];
    #pragma unroll
    for (int r = 0; r < 4; ++r) acc[r] = 0.0f;

    for (int fc = 0; fc < 128; fc += 32) {
        float xm[32];
        #pragma unroll
        for (int f = 0; f < 32; f += 4) {
            float4 v = *(float4*)&sm.s.Xs[m][fc + f];
            xm[f] = v.x; xm[f + 1] = v.y; xm[f + 2] = v.z; xm[f + 3] = v.w;
        }
        #pragma unroll
        for (int r = 0; r < 4; ++r) {
            int n = ch * 8 + rh * 4 + r;
            #pragma unroll
            for (int f = 0; f < 32; f += 4) {
                float4 v = *(float4*)&sm.s.Xs[n][fc + f];
                acc[r] = fmaf(xm[f], v.x,
                         fmaf(xm[f + 1], v.y,
                         fmaf(xm[f + 2], v.z,
                         fmaf(xm[f + 3], v.w, acc[r]))));
            }
        }
    }

    float nm = sm.s.nrm[m];
    size_t ob = (size_t)t * 2 * 16384;
    #pragma unroll
    for (int r = 0; r < 4; ++r) {
        int n = ch * 8 + rh * 4 + r;
        float denom = sm.s.nrm[n] * nm + 1e-6f;
        float sim = __fdividef(acc[r], denom);
        out[ob + (size_t)n * 128 + m] = fminf(fmaxf(sim, 0.0f), 1.0f);
        out[ob + 16384 + (size_t)n * 128 + m] = fminf(fmaxf(1.0f - sim, 0.0f), 1.0f);
    }
}

extern "C" void kernel_launch(void* const* d_in, const int* in_sizes, int n_in,
                              void* d_out, int out_size, void* d_ws, size_t ws_size,
                              hipStream_t stream) {
    const float* x0    = (const float*)d_in[0];
    const float* E     = (const float*)d_in[1];
    const float* ew    = (const float*)d_in[2];
    const float* eb    = (const float*)d_in[3];
    const float* cw    = (const float*)d_in[4];
    const float* nw    = (const float*)d_in[5];
    const float* gamma = (const float*)d_in[6];
    const float* beta  = (const float*)d_in[7];
    float* out = (float*)d_out;

    float* ws    = (float*)d_ws;
    float* x1    = ws;                 // 262144 floats
    float* yb    = ws + 262144;        // 262144 floats (y buffer, both layers)
    float* aggrP = ws + 524288;        // 4 x 262144 floats (quarter partials, non-atomic)
    float* bn    = ws + 1572864;       // 512 floats (256 per layer: sum | sumsq)
    float* WT    = ws + 1573376;       // 32768 floats (both layers), 16B-aligned

    // D1: sim_cal(x0) + W transpose + bn zero
    sim0_prep_k<<<dim3(16, 17), 256, 0, stream>>>(x0, nw, WT, bn, out);

    // D2: layer-0 edge pass
    edge_k<0><<<8192, 256, 0, stream>>>(x0, x0, E, ew, eb, aggrP);

    // D3: cooperative node+BN+sim, writes x1
    {
        const float* xa = x0; const float* ap = aggrP; const float* cwp = cw;
        const float* wt = WT; float* ybp = yb; float* bnp = bn;
        const float* ga = gamma; const float* be = beta;
        float* op = out + 524288; float* xo = x1;
        void* args[] = {(void*)&xa, (void*)&ap, (void*)&cwp, (void*)&wt, (void*)&ybp,
                        (void*)&bnp, (void*)&ga, (void*)&be, (void*)&op, (void*)&xo};
        hipLaunchCooperativeKernel((const void*)node_sim_k<true>, dim3(16, 16),
                                   dim3(256, 1, 1), args, 0, stream);
    }

    // D4: layer-1 edge pass (recompute e0 from original E)
    edge_k<1><<<8192, 256, 0, stream>>>(x0, x1, E, ew, eb, aggrP);

    // D5: cooperative node+BN+sim (no x writeback)
    {
        const float* xa = x1; const float* ap = aggrP; const float* cwp = cw + 2;
        const float* wt = WT + 16384; float* ybp = yb; float* bnp = bn + 256;
        const float* ga = gamma + 128; const float* be = beta + 128;
        float* op = out + 1048576; float* xo = nullptr;
        void* args[] = {(void*)&xa, (void*)&ap, (void*)&cwp, (void*)&wt, (void*)&ybp,
                        (void*)&bnp, (void*)&ga, (void*)&be, (void*)&op, (void*)&xo};
        hipLaunchCooperativeKernel((const void*)node_sim_k<false>, dim3(16, 16),
                                   dim3(256, 1, 1), args, 0, stream);
    }
}